// Round 14
// baseline (348.167 us; speedup 1.0000x reference)
//
#include <hip/hip_runtime.h>
#include <math.h>

#define NN 100000
#define SCALE 0.8408964152537145f  // inv_sqrt_tau(=2) * 32^-0.25
#define HALF_SCALE2 0.3535533905932738f // 0.5 * SCALE^2
#define RATIO 0.125f               // 64^-0.5
#define KEPS 1e-6f

// ws layout (float offsets)
#define WS_KMAX 0
#define WS_KVSKS 8          // 16384 kvs fp32 + 512 ks fp32
#define WS_KVST 16904       // kvsT bf16 [8][32][64] -> 8192 floats
#define WS_B2Q 156168       // 512
#define WS_B2K 156680       // 512
#define WS_W2QT 157192      // bf16 [512][128] -> 32768 floats
#define WS_W2KT 189960      // bf16 [512][128]
#define WS_WQST 222728      // bf16 [256][128] (SCALE*Wq)^T -> 16384 floats
#define WS_WOT 239112       // bf16 [128][256] Wo^T -> 16384 floats
#define WS_BQS 255496       // 256 fp32 (SCALE*Wq_b)
#define WS_WKVT 255752      // bf16 [512][128] [Wk|Wv]^T -> 32768 floats
#define WS_BKV 288520       // 512 fp32 [bk|bv]
#define WS_RED2 289032      // 8*16896 fp32 stage-2 reduce partials
#define WS_PART 424200      // nb * 16896

typedef __attribute__((ext_vector_type(8))) short short8;
typedef __attribute__((ext_vector_type(4))) float f32x4;

#define MFMA16(a, b, c) __builtin_amdgcn_mfma_f32_16x16x32_bf16((a), (b), (c), 0, 0, 0)

__device__ __forceinline__ short f2bf(float f) {
    union { float f; unsigned u; } a; a.f = f;
    unsigned r = a.u + 0x7fffu + ((a.u >> 16) & 1u);
    return (short)(r >> 16);
}
__device__ __forceinline__ float bf2f(short s) {
    union { float f; unsigned u; } a; a.u = ((unsigned)(unsigned short)s) << 16;
    return a.f;
}

__device__ __forceinline__ float bsum16(float v) {
    v += __shfl_xor(v, 1); v += __shfl_xor(v, 2);
    v += __shfl_xor(v, 4); v += __shfl_xor(v, 8);
    return v;
}
__device__ __forceinline__ float bmax16(float v) {
    v = fmaxf(v, __shfl_xor(v, 1)); v = fmaxf(v, __shfl_xor(v, 2));
    v = fmaxf(v, __shfl_xor(v, 4)); v = fmaxf(v, __shfl_xor(v, 8));
    return v;
}

__device__ __forceinline__ void atomicMaxFloat(float* addr, float val) {
    int* ai = (int*)addr;
    int cur = *((volatile int*)ai);
    while (val > __int_as_float(cur)) {
        int assumed = cur;
        cur = atomicCAS(ai, assumed, __float_as_int(val));
        if (cur == assumed) break;
    }
}

// ---------- prep (merged fold+prep): all weight transforms in one launch ----------
__global__ __launch_bounds__(256) void prep_kernel(
    const float* __restrict__ Wq_w, const float* __restrict__ Wq_b,
    const float* __restrict__ Wk_w, const float* __restrict__ Wk_b,
    const float* __restrict__ Wv_w, const float* __restrict__ Wv_b,
    const float* __restrict__ Wo_w, const float* __restrict__ proj,
    float* __restrict__ ws)
{
    if (blockIdx.x == 0 && threadIdx.x < 8) ws[WS_KMAX + threadIdx.x] = -1e30f;
    int idx = blockIdx.x * 256 + threadIdx.x;
    const int ftotal = 129 * 512;
    if (idx < 2 * ftotal) {  // fold: W2QT / W2KT + b2q / b2k
        const int mat = (idx >= ftotal) ? 1 : 0;
        idx -= mat * ftotal;
        const int row = idx >> 9;
        const int col = idx & 511;
        const int h = col >> 6, m = col & 63;
        const float* W = mat ? Wk_w : Wq_w;
        const float* b = mat ? Wk_b : Wq_b;
        const float* src = (row < 128) ? (W + row * 256 + h * 32) : (b + h * 32);
        float s = 0.f;
#pragma unroll
        for (int d = 0; d < 32; ++d) s = fmaf(src[d], proj[m * 32 + d], s);
        s *= SCALE;
        if (row < 128) ((short*)(ws + (mat ? WS_W2KT : WS_W2QT)))[col * 128 + row] = f2bf(s);
        else           ws[(mat ? WS_B2K : WS_B2Q) + col] = s;
        return;
    }
    idx -= 2 * ftotal;
    if (idx < 32768) {  // WqsT [256][128]
        int c = idx >> 7, k = idx & 127;
        ((short*)(ws + WS_WQST))[idx] = f2bf(SCALE * Wq_w[k * 256 + c]);
        return;
    }
    idx -= 32768;
    if (idx < 32768) {  // WoT [128][256]
        int o = idx >> 8, c = idx & 255;
        ((short*)(ws + WS_WOT))[idx] = f2bf(Wo_w[c * 128 + o]);
        return;
    }
    idx -= 32768;
    if (idx < 256) { ws[WS_BQS + idx] = SCALE * Wq_b[idx]; return; }
    idx -= 256;
    if (idx < 65536) {  // WkvT [512][128]
        int c = idx >> 7, k = idx & 127;
        ((short*)(ws + WS_WKVT))[idx] =
            f2bf(c < 256 ? Wk_w[k * 256 + c] : Wv_w[k * 256 + (c - 256)]);
        return;
    }
    idx -= 65536;
    if (idx < 512) ws[WS_BKV + idx] = (idx < 256) ? Wk_b[idx] : Wv_b[idx - 256];
}

// ---------- kmax: 512 threads, wave = head, persistent over 64-row tiles ----------
__global__ __launch_bounds__(512, 4) void kmax_mfma_kernel(
    const float* __restrict__ x, const float* __restrict__ ws, float* __restrict__ kmax)
{
    __shared__ char smem[16384];
    const short* w2kt = (const short*)(ws + WS_W2KT);
    const float* b2k = ws + WS_B2K;
    const int t = threadIdx.x, w = t >> 6, l = t & 63, lg = l >> 4, li = l & 15;
    float b2r[4];
#pragma unroll
    for (int nc = 0; nc < 4; ++nc) b2r[nc] = b2k[w * 64 + nc * 16 + li];
    short8 Bf[16];
#pragma unroll
    for (int kk = 0; kk < 4; ++kk)
#pragma unroll
        for (int nc = 0; nc < 4; ++nc)
            Bf[kk * 4 + nc] = *(const short8*)&w2kt[(w * 64 + nc * 16 + li) * 128 + kk * 32 + lg * 8];
    float mx = -1e30f;

    for (int tile = blockIdx.x; tile < 1563; tile += gridDim.x) {
        const int n0 = tile * 64;
        __syncthreads();
        {
            const int sr = t >> 3, sp = t & 7;
            float f[16];
            if (n0 + sr < NN) {
                const float* gp = x + (size_t)(n0 + sr) * 128 + sp * 16;
#pragma unroll
                for (int i = 0; i < 4; ++i) {
                    f32x4 v = *(const f32x4*)(gp + i * 4);
                    f[i*4] = v[0]; f[i*4+1] = v[1]; f[i*4+2] = v[2]; f[i*4+3] = v[3];
                }
            } else {
#pragma unroll
                for (int i = 0; i < 16; ++i) f[i] = 0.f;
            }
            const int rb = sr * 256, sw = (sr & 7) << 4;
#pragma unroll
            for (int j = 0; j < 2; ++j) {
                short8 s;
#pragma unroll
                for (int e = 0; e < 8; ++e) s[e] = f2bf(f[j * 8 + e]);
                *(short8*)(smem + rb + ((sp * 32 + 16 * j) ^ sw)) = s;
            }
        }
        __syncthreads();
#pragma unroll
        for (int mr = 0; mr < 4; ++mr) {
            f32x4 acc[4];
#pragma unroll
            for (int nc = 0; nc < 4; ++nc) acc[nc] = (f32x4){0.f, 0.f, 0.f, 0.f};
#pragma unroll
            for (int kk = 0; kk < 4; ++kk) {
                const int row = mr * 16 + li;
                const short8 a = *(const short8*)(smem + row * 256 + (((kk * 32 + lg * 8) * 2) ^ ((row & 7) << 4)));
#pragma unroll
                for (int nc = 0; nc < 4; ++nc) acc[nc] = MFMA16(a, Bf[kk * 4 + nc], acc[nc]);
            }
#pragma unroll
            for (int r = 0; r < 4; ++r) {
                if (n0 + mr * 16 + lg * 4 + r < NN) {
#pragma unroll
                    for (int nc = 0; nc < 4; ++nc) mx = fmaxf(mx, acc[nc][r] + b2r[nc]);
                }
            }
        }
    }
    mx = bmax16(mx); mx = fmaxf(mx, __shfl_xor(mx, 16)); mx = fmaxf(mx, __shfl_xor(mx, 32));
    if (l == 0) atomicMaxFloat(&kmax[w], mx);
}

// ---------- kvs: 512 threads, wave = head, weights hoisted to registers ----------
__global__ __launch_bounds__(512, 2) void kvs_mfma_kernel(
    const float* __restrict__ x, const float* __restrict__ ws,
    float* __restrict__ partials, int nb)
{
    __shared__ char smem[57344];
    const short* wkvt = (const short*)(ws + WS_WKVT);
    const short* w2kt = (const short*)(ws + WS_W2KT);
    const float* bkv  = ws + WS_BKV;
    const float* b2k  = ws + WS_B2K;
    const float* kmaxp = ws + WS_KMAX;

    const int t = threadIdx.x, w = t >> 6, l = t & 63, lg = l >> 4, li = l & 15;
    char* kptb = smem + 8192 + w * 4096;
    char* vtb  = smem + 40960 + w * 2048;
    float bkv_r[4], b2_r[4];
#pragma unroll
    for (int nc = 0; nc < 4; ++nc) {
        bkv_r[nc] = (nc < 2) ? bkv[w * 32 + nc * 16 + li] : bkv[256 + w * 32 + (nc - 2) * 16 + li];
        b2_r[nc]  = b2k[w * 64 + nc * 16 + li];
    }
    const float km = kmaxp[w];

    short8 Bkv[16], B2k[16];
#pragma unroll
    for (int hf = 0; hf < 2; ++hf)
#pragma unroll
        for (int kk = 0; kk < 4; ++kk)
#pragma unroll
            for (int nc = 0; nc < 2; ++nc) {
                const int brow = (hf == 0 ? w * 32 : 256 + w * 32) + nc * 16 + li;
                Bkv[hf * 8 + kk * 2 + nc] = *(const short8*)&wkvt[brow * 128 + kk * 32 + lg * 8];
                B2k[hf * 8 + kk * 2 + nc] =
                    *(const short8*)&w2kt[(w * 64 + (hf * 2 + nc) * 16 + li) * 128 + kk * 32 + lg * 8];
            }

    f32x4 ak[4][2];
#pragma unroll
    for (int mr = 0; mr < 4; ++mr)
#pragma unroll
        for (int nc = 0; nc < 2; ++nc) ak[mr][nc] = (f32x4){0.f,0.f,0.f,0.f};
    float ksacc[4];
#pragma unroll
    for (int nc = 0; nc < 4; ++nc) ksacc[nc] = 0.f;

    for (int tile = blockIdx.x; tile < 3125; tile += nb) {
        const int n0 = tile * 32;
        __syncthreads();
        {
            const int sr = t >> 4, sp = t & 15;
            const float* gp = x + (size_t)(n0 + sr) * 128 + sp * 8;
            f32x4 v0 = *(const f32x4*)gp, v1 = *(const f32x4*)(gp + 4);
            short8 s;
#pragma unroll
            for (int e = 0; e < 4; ++e) { s[e] = f2bf(v0[e]); s[4 + e] = f2bf(v1[e]); }
            *(short8*)(smem + sr * 256 + ((sp * 16) ^ ((sr & 7) << 4))) = s;
        }
        __syncthreads();
        float dgk[2][4];
#pragma unroll
        for (int hf = 0; hf < 2; ++hf) {
            f32x4 acc[2][2];
#pragma unroll
            for (int mr = 0; mr < 2; ++mr)
#pragma unroll
                for (int nc = 0; nc < 2; ++nc) acc[mr][nc] = (f32x4){0.f,0.f,0.f,0.f};
#pragma unroll
            for (int kk = 0; kk < 4; ++kk)
#pragma unroll
                for (int mr = 0; mr < 2; ++mr) {
                    const int row = mr * 16 + li;
                    const short8 a = *(const short8*)(smem + row * 256 + (((kk * 32 + lg * 8) * 2) ^ ((row & 7) << 4)));
#pragma unroll
                    for (int nc = 0; nc < 2; ++nc) acc[mr][nc] = MFMA16(a, Bkv[hf * 8 + kk * 2 + nc], acc[mr][nc]);
                }
            if (hf == 0) {
#pragma unroll
                for (int mr = 0; mr < 2; ++mr)
#pragma unroll
                    for (int r = 0; r < 4; ++r) {
                        const float v0 = acc[mr][0][r] + bkv_r[0];
                        const float v1 = acc[mr][1][r] + bkv_r[1];
                        dgk[mr][r] = HALF_SCALE2 * bsum16(v0 * v0 + v1 * v1);
                    }
            } else {
#pragma unroll
                for (int mr = 0; mr < 2; ++mr)
#pragma unroll
                    for (int nc = 0; nc < 2; ++nc) {
                        short4 s4;
                        s4.x = f2bf(acc[mr][nc][0] + bkv_r[2 + nc]);
                        s4.y = f2bf(acc[mr][nc][1] + bkv_r[2 + nc]);
                        s4.z = f2bf(acc[mr][nc][2] + bkv_r[2 + nc]);
                        s4.w = f2bf(acc[mr][nc][3] + bkv_r[2 + nc]);
                        const int vrow = nc * 16 + li;
                        const int b = 32 * mr + 8 * lg;
                        *(short4*)(vtb + vrow * 64 +
                                   ((((b >> 4) ^ ((vrow >> 1) & 3)) << 4) | (b & 15))) = s4;
                    }
            }
        }
#pragma unroll
        for (int hf = 0; hf < 2; ++hf) {
            f32x4 acd[2][2];
#pragma unroll
            for (int mr = 0; mr < 2; ++mr)
#pragma unroll
                for (int nc = 0; nc < 2; ++nc) acd[mr][nc] = (f32x4){0.f,0.f,0.f,0.f};
#pragma unroll
            for (int kk = 0; kk < 4; ++kk)
#pragma unroll
                for (int mr = 0; mr < 2; ++mr) {
                    const int row = mr * 16 + li;
                    const short8 a = *(const short8*)(smem + row * 256 + (((kk * 32 + lg * 8) * 2) ^ ((row & 7) << 4)));
#pragma unroll
                    for (int nc = 0; nc < 2; ++nc) acd[mr][nc] = MFMA16(a, B2k[hf * 8 + kk * 2 + nc], acd[mr][nc]);
                }
#pragma unroll
            for (int mr = 0; mr < 2; ++mr)
#pragma unroll
                for (int nc = 0; nc < 2; ++nc) {
                    short4 s4;
#pragma unroll
                    for (int r = 0; r < 4; ++r) {
                        const float val = acd[mr][nc][r] + b2_r[hf * 2 + nc];
                        const float kp = RATIO * (__expf(val - dgk[mr][r] - km) + KEPS);
                        const short sb = f2bf(kp);
                        ksacc[hf * 2 + nc] += bf2f(sb);
                        if (r == 0) s4.x = sb; else if (r == 1) s4.y = sb;
                        else if (r == 2) s4.z = sb; else s4.w = sb;
                    }
                    const int mrow = (hf * 2 + nc) * 16 + li;
                    const int b = 32 * mr + 8 * lg;
                    *(short4*)(kptb + mrow * 64 +
                               ((((b >> 4) ^ ((mrow >> 1) & 3)) << 4) | (b & 15))) = s4;
                }
        }
        {
            short8 aa[4], bv[2];
#pragma unroll
            for (int mr = 0; mr < 4; ++mr) {
                const int row = mr * 16 + li;
                aa[mr] = *(const short8*)(kptb + row * 64 + ((lg ^ ((row >> 1) & 3)) << 4));
            }
#pragma unroll
            for (int nc = 0; nc < 2; ++nc) {
                const int vrow = nc * 16 + li;
                bv[nc] = *(const short8*)(vtb + vrow * 64 + ((lg ^ ((vrow >> 1) & 3)) << 4));
            }
#pragma unroll
            for (int mr = 0; mr < 4; ++mr)
#pragma unroll
                for (int nc = 0; nc < 2; ++nc)
                    ak[mr][nc] = MFMA16(aa[mr], bv[nc], ak[mr][nc]);
        }
    }
    float* pb = partials + (size_t)blockIdx.x * 16896;
#pragma unroll
    for (int mr = 0; mr < 4; ++mr)
#pragma unroll
        for (int nc = 0; nc < 2; ++nc)
#pragma unroll
            for (int r = 0; r < 4; ++r) {
                const int m = mr * 16 + lg * 4 + r;
                const int d = nc * 16 + li;
                pb[(w * 64 + m) * 32 + d] = ak[mr][nc][r];
            }
#pragma unroll
    for (int nc = 0; nc < 4; ++nc) {
        float s = ksacc[nc];
        s += __shfl_xor(s, 16); s += __shfl_xor(s, 32);
        if (lg == 0) pb[16384 + w * 64 + nc * 16 + li] = s;
    }
}

// ---------- two-stage deterministic reduce ----------
__global__ __launch_bounds__(256) void reduce1_kernel(
    const float* __restrict__ partials, float* __restrict__ red2, int nb)
{
    const int b = blockIdx.x;
    const int part = b & 7, grp = b >> 3;
    const int idx = grp * 256 + threadIdx.x;
    if (idx >= 16896) return;
    const int per = (nb + 7) >> 3;
    const int lo = part * per;
    const int hi = (lo + per < nb) ? (lo + per) : nb;
    float s = 0.f;
    for (int q = lo; q < hi; ++q) s += partials[(size_t)q * 16896 + idx];
    red2[part * 16896 + idx] = s;
}

__global__ __launch_bounds__(256) void reduce2_kernel(
    const float* __restrict__ red2, float* __restrict__ ws)
{
    const int idx = blockIdx.x * 256 + threadIdx.x;
    if (idx >= 16896) return;
    float s = 0.f;
#pragma unroll
    for (int p = 0; p < 8; ++p) s += red2[p * 16896 + idx];
    ws[WS_KVSKS + idx] = s;
    if (idx < 16384) {
        const int h = idx >> 11, m = (idx >> 5) & 63, d = idx & 31;
        ((short*)(ws + WS_KVST))[(h * 32 + d) * 64 + m] = f2bf(s);
    }
}

// ---------- out: 512 threads, wave = head, 32 rows/block (R13-frozen) ----------
__global__ __launch_bounds__(512, 4) void out_mfma_kernel(
    const float* __restrict__ x, const float* __restrict__ ws,
    const float* __restrict__ alpha, const float* __restrict__ beta,
    const float* __restrict__ Wo_b, float* __restrict__ out)
{
    __shared__ char smem[40960];
    const short* wqst = (const short*)(ws + WS_WQST);
    const short* w2qt = (const short*)(ws + WS_W2QT);
    const short* wot  = (const short*)(ws + WS_WOT);
    const short* kvst = (const short*)(ws + WS_KVST);
    const float* bqs  = ws + WS_BQS;
    const float* b2q  = ws + WS_B2Q;
    const float* ksum = ws + WS_KVSKS + 16384;

    const int t = threadIdx.x, w = t >> 6, l = t & 63, lg = l >> 4, li = l & 15;
    const float a_ = __expf(alpha[0]), b_ = __expf(beta[0]);
    const float a2 = a_ * a_, bc = b_ * (a_ + 1.f);
    char* qpb = smem + 24576 + w * 2048;

    float bq_r[2], b2_r[4], ksv[4];
#pragma unroll
    for (int nc = 0; nc < 2; ++nc) bq_r[nc] = bqs[w * 32 + nc * 16 + li];
#pragma unroll
    for (int nc = 0; nc < 4; ++nc) {
        b2_r[nc] = b2q[w * 64 + nc * 16 + li];
        ksv[nc]  = ksum[w * 64 + nc * 16 + li];
    }
    const float bo = Wo_b[w * 16 + li];

    const int n0 = blockIdx.x * 32;
    f32x4 xr[2];
    {
        const int c4 = (t & 31) * 4;
#pragma unroll
        for (int i = 0; i < 2; ++i) {
            const int sr = (t >> 5) + i * 16;
            xr[i] = *(const f32x4*)(x + (size_t)(n0 + sr) * 128 + c4);
            short4 s4;
            s4.x = f2bf(xr[i][0]); s4.y = f2bf(xr[i][1]);
            s4.z = f2bf(xr[i][2]); s4.w = f2bf(xr[i][3]);
            *(short4*)(smem + sr * 256 + ((c4 * 2) ^ ((sr & 7) << 4))) = s4;
        }
    }
    __syncthreads();
    float dg[2][4];
    {
        short8 Bq[8];
#pragma unroll
        for (int kk = 0; kk < 4; ++kk)
#pragma unroll
            for (int nc = 0; nc < 2; ++nc)
                Bq[kk * 2 + nc] = *(const short8*)&wqst[(w * 32 + nc * 16 + li) * 128 + kk * 32 + lg * 8];
#pragma unroll
        for (int mr = 0; mr < 2; ++mr) {
            f32x4 aq[2];
#pragma unroll
            for (int nc = 0; nc < 2; ++nc) aq[nc] = (f32x4){0.f,0.f,0.f,0.f};
#pragma unroll
            for (int kk = 0; kk < 4; ++kk) {
                const int row = mr * 16 + li;
                const short8 a = *(const short8*)(smem + row * 256 + (((kk * 32 + lg * 8) * 2) ^ ((row & 7) << 4)));
#pragma unroll
                for (int nc = 0; nc < 2; ++nc) aq[nc] = MFMA16(a, Bq[kk * 2 + nc], aq[nc]);
            }
#pragma unroll
            for (int r = 0; r < 4; ++r) {
                const float v0 = aq[0][r] + bq_r[0], v1 = aq[1][r] + bq_r[1];
                dg[mr][r] = 0.5f * bsum16(v0 * v0 + v1 * v1);
            }
        }
    }
    short8 Kf[4];
#pragma unroll
    for (int kk = 0; kk < 2; ++kk)
#pragma unroll
        for (int nc = 0; nc < 2; ++nc)
            Kf[kk * 2 + nc] = *(const short8*)&kvst[(w * 32 + nc * 16 + li) * 64 + kk * 32 + lg * 8];
#pragma unroll
    for (int mr = 0; mr < 2; ++mr) {
        f32x4 ad[4];
#pragma unroll
        for (int hf = 0; hf < 2; ++hf) {
            short8 Bf[8];
#pragma unroll
            for (int kk = 0; kk < 4; ++kk)
#pragma unroll
                for (int nc = 0; nc < 2; ++nc)
                    Bf[kk * 2 + nc] = *(const short8*)&w2qt[(w * 64 + (hf * 2 + nc) * 16 + li) * 128 + kk * 32 + lg * 8];
            f32x4 a0 = (f32x4){0.f,0.f,0.f,0.f}, a1 = (f32x4){0.f,0.f,0.f,0.f};
#pragma unroll
            for (int kk = 0; kk < 4; ++kk) {
                const int row = mr * 16 + li;
                const short8 a = *(const short8*)(smem + row * 256 + (((kk * 32 + lg * 8) * 2) ^ ((row & 7) << 4)));
                a0 = MFMA16(a, Bf[kk * 2 + 0], a0);
                a1 = MFMA16(a, Bf[kk * 2 + 1], a1);
            }
            ad[hf * 2 + 0] = a0; ad[hf * 2 + 1] = a1;
        }
        float zd[4];
#pragma unroll
        for (int r = 0; r < 4; ++r) {
            float vv[4];
#pragma unroll
            for (int nc = 0; nc < 4; ++nc) vv[nc] = ad[nc][r] + b2_r[nc];
            float mx = fmaxf(fmaxf(vv[0], vv[1]), fmaxf(vv[2], vv[3]));
            mx = bmax16(mx);
            const int rr = lg * 4 + r;
            const int sw = (rr & 7) << 4;
            float z = 0.f;
#pragma unroll
            for (int nc = 0; nc < 4; ++nc) {
                const float e = RATIO * (__expf(vv[nc] - dg[mr][r] - mx) + KEPS);
                z = fmaf(e, ksv[nc], z);
                *(short*)(qpb + rr * 128 + ((nc * 32 + 2 * li) ^ sw)) = f2bf(e);
            }
            zd[r] = bsum16(z);
        }
        f32x4 az[2];
#pragma unroll
        for (int nc = 0; nc < 2; ++nc) az[nc] = (f32x4){0.f,0.f,0.f,0.f};
#pragma unroll
        for (int kk = 0; kk < 2; ++kk) {
            const short8 aa = *(const short8*)(qpb + li * 128 +
                              ((kk * 64 + lg * 16) ^ ((li & 7) << 4)));
#pragma unroll
            for (int nc = 0; nc < 2; ++nc) az[nc] = MFMA16(aa, Kf[kk * 2 + nc], az[nc]);
        }
#pragma unroll
        for (int nc = 0; nc < 2; ++nc)
#pragma unroll
            for (int r = 0; r < 4; ++r) {
                const int row = mr * 16 + lg * 4 + r;
                const float zv = az[nc][r] / zd[r];
                *(short*)(smem + 8192 + row * 512 +
                    ((2 * (w * 32 + nc * 16 + li)) ^ ((row & 7) << 4))) = f2bf(zv);
            }
    }
    short8 Bo[8];
#pragma unroll
    for (int kk = 0; kk < 8; ++kk)
        Bo[kk] = *(const short8*)&wot[(w * 16 + li) * 256 + kk * 32 + lg * 8];
    __syncthreads();
    f32x4 ao[2];
#pragma unroll
    for (int mr = 0; mr < 2; ++mr) ao[mr] = (f32x4){0.f,0.f,0.f,0.f};
#pragma unroll
    for (int mr = 0; mr < 2; ++mr)
#pragma unroll
        for (int kk = 0; kk < 8; ++kk) {
            const int row = mr * 16 + li;
            const short8 aa = *(const short8*)(smem + 8192 + row * 512 +
                              ((kk * 64 + lg * 16) ^ ((row & 7) << 4)));
            ao[mr] = MFMA16(aa, Bo[kk], ao[mr]);
        }
    __syncthreads();
    float* xnb = (float*)smem;
#pragma unroll
    for (int mr = 0; mr < 2; ++mr)
#pragma unroll
        for (int r = 0; r < 4; ++r) {
            const int row = mr * 16 + lg * 4 + r;
            xnb[row * 132 + w * 16 + li] = ao[mr][r] + bo;
        }
    __syncthreads();
    {
        const int c4 = (t & 31) * 4;
#pragma unroll
        for (int i = 0; i < 2; ++i) {
            const int sr = (t >> 5) + i * 16;
            const f32x4 xn4 = *(const f32x4*)&xnb[sr * 132 + c4];
            f32x4 o4;
            o4[0] = a2 * xr[i][0] + bc * xn4[0];
            o4[1] = a2 * xr[i][1] + bc * xn4[1];
            o4[2] = a2 * xr[i][2] + bc * xn4[2];
            o4[3] = a2 * xr[i][3] + bc * xn4[3];
            *(f32x4*)(out + (size_t)(n0 + sr) * 128 + c4) = o4;
        }
    }
}

extern "C" void kernel_launch(void* const* d_in, const int* in_sizes, int n_in,
                              void* d_out, int out_size, void* d_ws, size_t ws_size,
                              hipStream_t stream) {
    (void)in_sizes; (void)n_in; (void)out_size;
    const float* x    = (const float*)d_in[0];
    const float* Wq_w = (const float*)d_in[2];
    const float* Wq_b = (const float*)d_in[3];
    const float* Wk_w = (const float*)d_in[4];
    const float* Wk_b = (const float*)d_in[5];
    const float* Wv_w = (const float*)d_in[6];
    const float* Wv_b = (const float*)d_in[7];
    const float* Wo_w = (const float*)d_in[8];
    const float* Wo_b = (const float*)d_in[9];
    const float* alpha= (const float*)d_in[10];
    const float* beta = (const float*)d_in[11];
    const float* proj = (const float*)d_in[12];
    float* out = (float*)d_out;
    float* ws  = (float*)d_ws;

    float* kmax     = ws + WS_KMAX;
    float* red2     = ws + WS_RED2;
    float* partials = ws + WS_PART;
    const size_t availf = (ws_size / 4 > (size_t)WS_PART) ? (ws_size / 4 - WS_PART) : 0;
    int nb = (int)(availf / 16896);
    if (nb > 512) nb = 512;
    if (nb < 1) nb = 1;

    prep_kernel<<<1032, 256, 0, stream>>>(Wq_w, Wq_b, Wk_w, Wk_b, Wv_w, Wv_b, Wo_w, proj, ws);
    kmax_mfma_kernel<<<768, 512, 0, stream>>>(x, ws, kmax);
    kvs_mfma_kernel<<<nb, 512, 0, stream>>>(x, ws, partials, nb);
    reduce1_kernel<<<528, 256, 0, stream>>>(partials, red2, nb);
    reduce2_kernel<<<66, 256, 0, stream>>>(red2, ws);
    out_mfma_kernel<<<3125, 512, 0, stream>>>(x, ws, alpha, beta, Wo_b, out);
}

// Round 15
// 303.600 us; speedup vs baseline: 1.1468x; 1.1468x over previous
//
#include <hip/hip_runtime.h>
#include <math.h>

#define NN 100000
#define SCALE 0.8408964152537145f  // inv_sqrt_tau(=2) * 32^-0.25
#define HALF_SCALE2 0.3535533905932738f // 0.5 * SCALE^2
#define RATIO 0.125f               // 64^-0.5
#define KEPS 1e-6f

// ws layout (float offsets)
#define WS_KMAX 0
#define WS_KVSKS 8          // 16384 kvs fp32 + 512 ks fp32
#define WS_KVST 16904       // kvsT bf16 [8][32][64] -> 8192 floats
#define WS_B2Q 156168       // 512
#define WS_B2K 156680       // 512
#define WS_W2QT 157192      // bf16 [512][128] -> 32768 floats
#define WS_W2KT 189960      // bf16 [512][128]
#define WS_WQST 222728      // bf16 [256][128] (SCALE*Wq)^T -> 16384 floats
#define WS_WOT 239112       // bf16 [128][256] Wo^T -> 16384 floats
#define WS_BQS 255496       // 256 fp32 (SCALE*Wq_b)
#define WS_WKVT 255752      // bf16 [512][128] [Wk|Wv]^T -> 32768 floats
#define WS_BKV 288520       // 512 fp32 [bk|bv]
#define WS_RED2 289032      // 8*16896 fp32 stage-2 reduce partials
#define WS_PART 424200      // nb * 16896

typedef __attribute__((ext_vector_type(8))) short short8;
typedef __attribute__((ext_vector_type(4))) float f32x4;

#define MFMA16(a, b, c) __builtin_amdgcn_mfma_f32_16x16x32_bf16((a), (b), (c), 0, 0, 0)

__device__ __forceinline__ short f2bf(float f) {
    union { float f; unsigned u; } a; a.f = f;
    unsigned r = a.u + 0x7fffu + ((a.u >> 16) & 1u);
    return (short)(r >> 16);
}
__device__ __forceinline__ float bf2f(short s) {
    union { float f; unsigned u; } a; a.u = ((unsigned)(unsigned short)s) << 16;
    return a.f;
}

__device__ __forceinline__ float bsum16(float v) {
    v += __shfl_xor(v, 1); v += __shfl_xor(v, 2);
    v += __shfl_xor(v, 4); v += __shfl_xor(v, 8);
    return v;
}
__device__ __forceinline__ float bmax16(float v) {
    v = fmaxf(v, __shfl_xor(v, 1)); v = fmaxf(v, __shfl_xor(v, 2));
    v = fmaxf(v, __shfl_xor(v, 4)); v = fmaxf(v, __shfl_xor(v, 8));
    return v;
}

__device__ __forceinline__ void atomicMaxFloat(float* addr, float val) {
    int* ai = (int*)addr;
    int cur = *((volatile int*)ai);
    while (val > __int_as_float(cur)) {
        int assumed = cur;
        cur = atomicCAS(ai, assumed, __float_as_int(val));
        if (cur == assumed) break;
    }
}

// ---------- prep (merged fold+prep): all weight transforms in one launch ----------
__global__ __launch_bounds__(256) void prep_kernel(
    const float* __restrict__ Wq_w, const float* __restrict__ Wq_b,
    const float* __restrict__ Wk_w, const float* __restrict__ Wk_b,
    const float* __restrict__ Wv_w, const float* __restrict__ Wv_b,
    const float* __restrict__ Wo_w, const float* __restrict__ proj,
    float* __restrict__ ws)
{
    if (blockIdx.x == 0 && threadIdx.x < 8) ws[WS_KMAX + threadIdx.x] = -1e30f;
    int idx = blockIdx.x * 256 + threadIdx.x;
    const int ftotal = 129 * 512;
    if (idx < 2 * ftotal) {  // fold: W2QT / W2KT + b2q / b2k
        const int mat = (idx >= ftotal) ? 1 : 0;
        idx -= mat * ftotal;
        const int row = idx >> 9;
        const int col = idx & 511;
        const int h = col >> 6, m = col & 63;
        const float* W = mat ? Wk_w : Wq_w;
        const float* b = mat ? Wk_b : Wq_b;
        const float* src = (row < 128) ? (W + row * 256 + h * 32) : (b + h * 32);
        float s = 0.f;
#pragma unroll
        for (int d = 0; d < 32; ++d) s = fmaf(src[d], proj[m * 32 + d], s);
        s *= SCALE;
        if (row < 128) ((short*)(ws + (mat ? WS_W2KT : WS_W2QT)))[col * 128 + row] = f2bf(s);
        else           ws[(mat ? WS_B2K : WS_B2Q) + col] = s;
        return;
    }
    idx -= 2 * ftotal;
    if (idx < 32768) {  // WqsT [256][128]
        int c = idx >> 7, k = idx & 127;
        ((short*)(ws + WS_WQST))[idx] = f2bf(SCALE * Wq_w[k * 256 + c]);
        return;
    }
    idx -= 32768;
    if (idx < 32768) {  // WoT [128][256]
        int o = idx >> 8, c = idx & 255;
        ((short*)(ws + WS_WOT))[idx] = f2bf(Wo_w[c * 128 + o]);
        return;
    }
    idx -= 32768;
    if (idx < 256) { ws[WS_BQS + idx] = SCALE * Wq_b[idx]; return; }
    idx -= 256;
    if (idx < 65536) {  // WkvT [512][128]
        int c = idx >> 7, k = idx & 127;
        ((short*)(ws + WS_WKVT))[idx] =
            f2bf(c < 256 ? Wk_w[k * 256 + c] : Wv_w[k * 256 + (c - 256)]);
        return;
    }
    idx -= 65536;
    if (idx < 512) ws[WS_BKV + idx] = (idx < 256) ? Wk_b[idx] : Wv_b[idx - 256];
}

// ---------- kmax: 512 threads, wave = head, persistent over 64-row tiles ----------
__global__ __launch_bounds__(512, 4) void kmax_mfma_kernel(
    const float* __restrict__ x, const float* __restrict__ ws, float* __restrict__ kmax)
{
    __shared__ char smem[16384];
    const short* w2kt = (const short*)(ws + WS_W2KT);
    const float* b2k = ws + WS_B2K;
    const int t = threadIdx.x, w = t >> 6, l = t & 63, lg = l >> 4, li = l & 15;
    float b2r[4];
#pragma unroll
    for (int nc = 0; nc < 4; ++nc) b2r[nc] = b2k[w * 64 + nc * 16 + li];
    short8 Bf[16];
#pragma unroll
    for (int kk = 0; kk < 4; ++kk)
#pragma unroll
        for (int nc = 0; nc < 4; ++nc)
            Bf[kk * 4 + nc] = *(const short8*)&w2kt[(w * 64 + nc * 16 + li) * 128 + kk * 32 + lg * 8];
    float mx = -1e30f;

    for (int tile = blockIdx.x; tile < 1563; tile += gridDim.x) {
        const int n0 = tile * 64;
        __syncthreads();
        {
            const int sr = t >> 3, sp = t & 7;
            float f[16];
            if (n0 + sr < NN) {
                const float* gp = x + (size_t)(n0 + sr) * 128 + sp * 16;
#pragma unroll
                for (int i = 0; i < 4; ++i) {
                    f32x4 v = *(const f32x4*)(gp + i * 4);
                    f[i*4] = v[0]; f[i*4+1] = v[1]; f[i*4+2] = v[2]; f[i*4+3] = v[3];
                }
            } else {
#pragma unroll
                for (int i = 0; i < 16; ++i) f[i] = 0.f;
            }
            const int rb = sr * 256, sw = (sr & 7) << 4;
#pragma unroll
            for (int j = 0; j < 2; ++j) {
                short8 s;
#pragma unroll
                for (int e = 0; e < 8; ++e) s[e] = f2bf(f[j * 8 + e]);
                *(short8*)(smem + rb + ((sp * 32 + 16 * j) ^ sw)) = s;
            }
        }
        __syncthreads();
#pragma unroll
        for (int mr = 0; mr < 4; ++mr) {
            f32x4 acc[4];
#pragma unroll
            for (int nc = 0; nc < 4; ++nc) acc[nc] = (f32x4){0.f, 0.f, 0.f, 0.f};
#pragma unroll
            for (int kk = 0; kk < 4; ++kk) {
                const int row = mr * 16 + li;
                const short8 a = *(const short8*)(smem + row * 256 + (((kk * 32 + lg * 8) * 2) ^ ((row & 7) << 4)));
#pragma unroll
                for (int nc = 0; nc < 4; ++nc) acc[nc] = MFMA16(a, Bf[kk * 4 + nc], acc[nc]);
            }
#pragma unroll
            for (int r = 0; r < 4; ++r) {
                if (n0 + mr * 16 + lg * 4 + r < NN) {
#pragma unroll
                    for (int nc = 0; nc < 4; ++nc) mx = fmaxf(mx, acc[nc][r] + b2r[nc]);
                }
            }
        }
    }
    mx = bmax16(mx); mx = fmaxf(mx, __shfl_xor(mx, 16)); mx = fmaxf(mx, __shfl_xor(mx, 32));
    if (l == 0) atomicMaxFloat(&kmax[w], mx);
}

// ---------- kvs: 512 threads, wave = head, weights hoisted to registers ----------
__global__ __launch_bounds__(512, 2) void kvs_mfma_kernel(
    const float* __restrict__ x, const float* __restrict__ ws,
    float* __restrict__ partials, int nb)
{
    __shared__ char smem[57344];
    const short* wkvt = (const short*)(ws + WS_WKVT);
    const short* w2kt = (const short*)(ws + WS_W2KT);
    const float* bkv  = ws + WS_BKV;
    const float* b2k  = ws + WS_B2K;
    const float* kmaxp = ws + WS_KMAX;

    const int t = threadIdx.x, w = t >> 6, l = t & 63, lg = l >> 4, li = l & 15;
    char* kptb = smem + 8192 + w * 4096;
    char* vtb  = smem + 40960 + w * 2048;
    float bkv_r[4], b2_r[4];
#pragma unroll
    for (int nc = 0; nc < 4; ++nc) {
        bkv_r[nc] = (nc < 2) ? bkv[w * 32 + nc * 16 + li] : bkv[256 + w * 32 + (nc - 2) * 16 + li];
        b2_r[nc]  = b2k[w * 64 + nc * 16 + li];
    }
    const float km = kmaxp[w];

    short8 Bkv[16], B2k[16];
#pragma unroll
    for (int hf = 0; hf < 2; ++hf)
#pragma unroll
        for (int kk = 0; kk < 4; ++kk)
#pragma unroll
            for (int nc = 0; nc < 2; ++nc) {
                const int brow = (hf == 0 ? w * 32 : 256 + w * 32) + nc * 16 + li;
                Bkv[hf * 8 + kk * 2 + nc] = *(const short8*)&wkvt[brow * 128 + kk * 32 + lg * 8];
                B2k[hf * 8 + kk * 2 + nc] =
                    *(const short8*)&w2kt[(w * 64 + (hf * 2 + nc) * 16 + li) * 128 + kk * 32 + lg * 8];
            }

    f32x4 ak[4][2];
#pragma unroll
    for (int mr = 0; mr < 4; ++mr)
#pragma unroll
        for (int nc = 0; nc < 2; ++nc) ak[mr][nc] = (f32x4){0.f,0.f,0.f,0.f};
    float ksacc[4];
#pragma unroll
    for (int nc = 0; nc < 4; ++nc) ksacc[nc] = 0.f;

    for (int tile = blockIdx.x; tile < 3125; tile += nb) {
        const int n0 = tile * 32;
        __syncthreads();
        {
            const int sr = t >> 4, sp = t & 15;
            const float* gp = x + (size_t)(n0 + sr) * 128 + sp * 8;
            f32x4 v0 = *(const f32x4*)gp, v1 = *(const f32x4*)(gp + 4);
            short8 s;
#pragma unroll
            for (int e = 0; e < 4; ++e) { s[e] = f2bf(v0[e]); s[4 + e] = f2bf(v1[e]); }
            *(short8*)(smem + sr * 256 + ((sp * 16) ^ ((sr & 7) << 4))) = s;
        }
        __syncthreads();
        float dgk[2][4];
#pragma unroll
        for (int hf = 0; hf < 2; ++hf) {
            f32x4 acc[2][2];
#pragma unroll
            for (int mr = 0; mr < 2; ++mr)
#pragma unroll
                for (int nc = 0; nc < 2; ++nc) acc[mr][nc] = (f32x4){0.f,0.f,0.f,0.f};
#pragma unroll
            for (int kk = 0; kk < 4; ++kk)
#pragma unroll
                for (int mr = 0; mr < 2; ++mr) {
                    const int row = mr * 16 + li;
                    const short8 a = *(const short8*)(smem + row * 256 + (((kk * 32 + lg * 8) * 2) ^ ((row & 7) << 4)));
#pragma unroll
                    for (int nc = 0; nc < 2; ++nc) acc[mr][nc] = MFMA16(a, Bkv[hf * 8 + kk * 2 + nc], acc[mr][nc]);
                }
            if (hf == 0) {
#pragma unroll
                for (int mr = 0; mr < 2; ++mr)
#pragma unroll
                    for (int r = 0; r < 4; ++r) {
                        const float v0 = acc[mr][0][r] + bkv_r[0];
                        const float v1 = acc[mr][1][r] + bkv_r[1];
                        dgk[mr][r] = HALF_SCALE2 * bsum16(v0 * v0 + v1 * v1);
                    }
            } else {
#pragma unroll
                for (int mr = 0; mr < 2; ++mr)
#pragma unroll
                    for (int nc = 0; nc < 2; ++nc) {
                        short4 s4;
                        s4.x = f2bf(acc[mr][nc][0] + bkv_r[2 + nc]);
                        s4.y = f2bf(acc[mr][nc][1] + bkv_r[2 + nc]);
                        s4.z = f2bf(acc[mr][nc][2] + bkv_r[2 + nc]);
                        s4.w = f2bf(acc[mr][nc][3] + bkv_r[2 + nc]);
                        const int vrow = nc * 16 + li;
                        const int b = 32 * mr + 8 * lg;
                        *(short4*)(vtb + vrow * 64 +
                                   ((((b >> 4) ^ ((vrow >> 1) & 3)) << 4) | (b & 15))) = s4;
                    }
            }
        }
#pragma unroll
        for (int hf = 0; hf < 2; ++hf) {
            f32x4 acd[2][2];
#pragma unroll
            for (int mr = 0; mr < 2; ++mr)
#pragma unroll
                for (int nc = 0; nc < 2; ++nc) acd[mr][nc] = (f32x4){0.f,0.f,0.f,0.f};
#pragma unroll
            for (int kk = 0; kk < 4; ++kk)
#pragma unroll
                for (int mr = 0; mr < 2; ++mr) {
                    const int row = mr * 16 + li;
                    const short8 a = *(const short8*)(smem + row * 256 + (((kk * 32 + lg * 8) * 2) ^ ((row & 7) << 4)));
#pragma unroll
                    for (int nc = 0; nc < 2; ++nc) acd[mr][nc] = MFMA16(a, B2k[hf * 8 + kk * 2 + nc], acd[mr][nc]);
                }
#pragma unroll
            for (int mr = 0; mr < 2; ++mr)
#pragma unroll
                for (int nc = 0; nc < 2; ++nc) {
                    short4 s4;
#pragma unroll
                    for (int r = 0; r < 4; ++r) {
                        const float val = acd[mr][nc][r] + b2_r[hf * 2 + nc];
                        const float kp = RATIO * (__expf(val - dgk[mr][r] - km) + KEPS);
                        const short sb = f2bf(kp);
                        ksacc[hf * 2 + nc] += bf2f(sb);
                        if (r == 0) s4.x = sb; else if (r == 1) s4.y = sb;
                        else if (r == 2) s4.z = sb; else s4.w = sb;
                    }
                    const int mrow = (hf * 2 + nc) * 16 + li;
                    const int b = 32 * mr + 8 * lg;
                    *(short4*)(kptb + mrow * 64 +
                               ((((b >> 4) ^ ((mrow >> 1) & 3)) << 4) | (b & 15))) = s4;
                }
        }
        {
            short8 aa[4], bv[2];
#pragma unroll
            for (int mr = 0; mr < 4; ++mr) {
                const int row = mr * 16 + li;
                aa[mr] = *(const short8*)(kptb + row * 64 + ((lg ^ ((row >> 1) & 3)) << 4));
            }
#pragma unroll
            for (int nc = 0; nc < 2; ++nc) {
                const int vrow = nc * 16 + li;
                bv[nc] = *(const short8*)(vtb + vrow * 64 + ((lg ^ ((vrow >> 1) & 3)) << 4));
            }
#pragma unroll
            for (int mr = 0; mr < 4; ++mr)
#pragma unroll
                for (int nc = 0; nc < 2; ++nc)
                    ak[mr][nc] = MFMA16(aa[mr], bv[nc], ak[mr][nc]);
        }
    }
    float* pb = partials + (size_t)blockIdx.x * 16896;
#pragma unroll
    for (int mr = 0; mr < 4; ++mr)
#pragma unroll
        for (int nc = 0; nc < 2; ++nc)
#pragma unroll
            for (int r = 0; r < 4; ++r) {
                const int m = mr * 16 + lg * 4 + r;
                const int d = nc * 16 + li;
                pb[(w * 64 + m) * 32 + d] = ak[mr][nc][r];
            }
#pragma unroll
    for (int nc = 0; nc < 4; ++nc) {
        float s = ksacc[nc];
        s += __shfl_xor(s, 16); s += __shfl_xor(s, 32);
        if (lg == 0) pb[16384 + w * 64 + nc * 16 + li] = s;
    }
}

// ---------- two-stage deterministic reduce ----------
__global__ __launch_bounds__(256) void reduce1_kernel(
    const float* __restrict__ partials, float* __restrict__ red2, int nb)
{
    const int b = blockIdx.x;
    const int part = b & 7, grp = b >> 3;
    const int idx = grp * 256 + threadIdx.x;
    if (idx >= 16896) return;
    const int per = (nb + 7) >> 3;
    const int lo = part * per;
    const int hi = (lo + per < nb) ? (lo + per) : nb;
    float s = 0.f;
    for (int q = lo; q < hi; ++q) s += partials[(size_t)q * 16896 + idx];
    red2[part * 16896 + idx] = s;
}

__global__ __launch_bounds__(256) void reduce2_kernel(
    const float* __restrict__ red2, float* __restrict__ ws)
{
    const int idx = blockIdx.x * 256 + threadIdx.x;
    if (idx >= 16896) return;
    float s = 0.f;
#pragma unroll
    for (int p = 0; p < 8; ++p) s += red2[p * 16896 + idx];
    ws[WS_KVSKS + idx] = s;
    if (idx < 16384) {
        const int h = idx >> 11, m = (idx >> 5) & 63, d = idx & 31;
        ((short*)(ws + WS_KVST))[(h * 32 + d) * 64 + m] = f2bf(s);
    }
}

// ---------- out: 512 threads, wave = head, 32 rows/block (R13-frozen) ----------
__global__ __launch_bounds__(512, 4) void out_mfma_kernel(
    const float* __restrict__ x, const float* __restrict__ ws,
    const float* __restrict__ alpha, const float* __restrict__ beta,
    const float* __restrict__ Wo_b, float* __restrict__ out)
{
    __shared__ char smem[40960];
    const short* wqst = (const short*)(ws + WS_WQST);
    const short* w2qt = (const short*)(ws + WS_W2QT);
    const short* wot  = (const short*)(ws + WS_WOT);
    const short* kvst = (const short*)(ws + WS_KVST);
    const float* bqs  = ws + WS_BQS;
    const float* b2q  = ws + WS_B2Q;
    const float* ksum = ws + WS_KVSKS + 16384;

    const int t = threadIdx.x, w = t >> 6, l = t & 63, lg = l >> 4, li = l & 15;
    const float a_ = __expf(alpha[0]), b_ = __expf(beta[0]);
    const float a2 = a_ * a_, bc = b_ * (a_ + 1.f);
    char* qpb = smem + 24576 + w * 2048;

    float bq_r[2], b2_r[4], ksv[4];
#pragma unroll
    for (int nc = 0; nc < 2; ++nc) bq_r[nc] = bqs[w * 32 + nc * 16 + li];
#pragma unroll
    for (int nc = 0; nc < 4; ++nc) {
        b2_r[nc] = b2q[w * 64 + nc * 16 + li];
        ksv[nc]  = ksum[w * 64 + nc * 16 + li];
    }
    const float bo = Wo_b[w * 16 + li];

    const int n0 = blockIdx.x * 32;
    f32x4 xr[2];
    {
        const int c4 = (t & 31) * 4;
#pragma unroll
        for (int i = 0; i < 2; ++i) {
            const int sr = (t >> 5) + i * 16;
            xr[i] = *(const f32x4*)(x + (size_t)(n0 + sr) * 128 + c4);
            short4 s4;
            s4.x = f2bf(xr[i][0]); s4.y = f2bf(xr[i][1]);
            s4.z = f2bf(xr[i][2]); s4.w = f2bf(xr[i][3]);
            *(short4*)(smem + sr * 256 + ((c4 * 2) ^ ((sr & 7) << 4))) = s4;
        }
    }
    __syncthreads();
    float dg[2][4];
    {
        short8 Bq[8];
#pragma unroll
        for (int kk = 0; kk < 4; ++kk)
#pragma unroll
            for (int nc = 0; nc < 2; ++nc)
                Bq[kk * 2 + nc] = *(const short8*)&wqst[(w * 32 + nc * 16 + li) * 128 + kk * 32 + lg * 8];
#pragma unroll
        for (int mr = 0; mr < 2; ++mr) {
            f32x4 aq[2];
#pragma unroll
            for (int nc = 0; nc < 2; ++nc) aq[nc] = (f32x4){0.f,0.f,0.f,0.f};
#pragma unroll
            for (int kk = 0; kk < 4; ++kk) {
                const int row = mr * 16 + li;
                const short8 a = *(const short8*)(smem + row * 256 + (((kk * 32 + lg * 8) * 2) ^ ((row & 7) << 4)));
#pragma unroll
                for (int nc = 0; nc < 2; ++nc) aq[nc] = MFMA16(a, Bq[kk * 2 + nc], aq[nc]);
            }
#pragma unroll
            for (int r = 0; r < 4; ++r) {
                const float v0 = aq[0][r] + bq_r[0], v1 = aq[1][r] + bq_r[1];
                dg[mr][r] = 0.5f * bsum16(v0 * v0 + v1 * v1);
            }
        }
    }
    short8 Kf[4];
#pragma unroll
    for (int kk = 0; kk < 2; ++kk)
#pragma unroll
        for (int nc = 0; nc < 2; ++nc)
            Kf[kk * 2 + nc] = *(const short8*)&kvst[(w * 32 + nc * 16 + li) * 64 + kk * 32 + lg * 8];
#pragma unroll
    for (int mr = 0; mr < 2; ++mr) {
        f32x4 ad[4];
#pragma unroll
        for (int hf = 0; hf < 2; ++hf) {
            short8 Bf[8];
#pragma unroll
            for (int kk = 0; kk < 4; ++kk)
#pragma unroll
                for (int nc = 0; nc < 2; ++nc)
                    Bf[kk * 2 + nc] = *(const short8*)&w2qt[(w * 64 + (hf * 2 + nc) * 16 + li) * 128 + kk * 32 + lg * 8];
            f32x4 a0 = (f32x4){0.f,0.f,0.f,0.f}, a1 = (f32x4){0.f,0.f,0.f,0.f};
#pragma unroll
            for (int kk = 0; kk < 4; ++kk) {
                const int row = mr * 16 + li;
                const short8 a = *(const short8*)(smem + row * 256 + (((kk * 32 + lg * 8) * 2) ^ ((row & 7) << 4)));
                a0 = MFMA16(a, Bf[kk * 2 + 0], a0);
                a1 = MFMA16(a, Bf[kk * 2 + 1], a1);
            }
            ad[hf * 2 + 0] = a0; ad[hf * 2 + 1] = a1;
        }
        float zd[4];
#pragma unroll
        for (int r = 0; r < 4; ++r) {
            float vv[4];
#pragma unroll
            for (int nc = 0; nc < 4; ++nc) vv[nc] = ad[nc][r] + b2_r[nc];
            float mx = fmaxf(fmaxf(vv[0], vv[1]), fmaxf(vv[2], vv[3]));
            mx = bmax16(mx);
            const int rr = lg * 4 + r;
            const int sw = (rr & 7) << 4;
            float z = 0.f;
#pragma unroll
            for (int nc = 0; nc < 4; ++nc) {
                const float e = RATIO * (__expf(vv[nc] - dg[mr][r] - mx) + KEPS);
                z = fmaf(e, ksv[nc], z);
                *(short*)(qpb + rr * 128 + ((nc * 32 + 2 * li) ^ sw)) = f2bf(e);
            }
            zd[r] = bsum16(z);
        }
        f32x4 az[2];
#pragma unroll
        for (int nc = 0; nc < 2; ++nc) az[nc] = (f32x4){0.f,0.f,0.f,0.f};
#pragma unroll
        for (int kk = 0; kk < 2; ++kk) {
            const short8 aa = *(const short8*)(qpb + li * 128 +
                              ((kk * 64 + lg * 16) ^ ((li & 7) << 4)));
#pragma unroll
            for (int nc = 0; nc < 2; ++nc) az[nc] = MFMA16(aa, Kf[kk * 2 + nc], az[nc]);
        }
#pragma unroll
        for (int nc = 0; nc < 2; ++nc)
#pragma unroll
            for (int r = 0; r < 4; ++r) {
                const int row = mr * 16 + lg * 4 + r;
                const float zv = az[nc][r] / zd[r];
                *(short*)(smem + 8192 + row * 512 +
                    ((2 * (w * 32 + nc * 16 + li)) ^ ((row & 7) << 4))) = f2bf(zv);
            }
    }
    short8 Bo[8];
#pragma unroll
    for (int kk = 0; kk < 8; ++kk)
        Bo[kk] = *(const short8*)&wot[(w * 16 + li) * 256 + kk * 32 + lg * 8];
    __syncthreads();
    f32x4 ao[2];
#pragma unroll
    for (int mr = 0; mr < 2; ++mr) ao[mr] = (f32x4){0.f,0.f,0.f,0.f};
#pragma unroll
    for (int mr = 0; mr < 2; ++mr)
#pragma unroll
        for (int kk = 0; kk < 8; ++kk) {
            const int row = mr * 16 + li;
            const short8 aa = *(const short8*)(smem + 8192 + row * 512 +
                              ((kk * 64 + lg * 16) ^ ((row & 7) << 4)));
            ao[mr] = MFMA16(aa, Bo[kk], ao[mr]);
        }
    __syncthreads();
    float* xnb = (float*)smem;
#pragma unroll
    for (int mr = 0; mr < 2; ++mr)
#pragma unroll
        for (int r = 0; r < 4; ++r) {
            const int row = mr * 16 + lg * 4 + r;
            xnb[row * 132 + w * 16 + li] = ao[mr][r] + bo;
        }
    __syncthreads();
    {
        const int c4 = (t & 31) * 4;
#pragma unroll
        for (int i = 0; i < 2; ++i) {
            const int sr = (t >> 5) + i * 16;
            const f32x4 xn4 = *(const f32x4*)&xnb[sr * 132 + c4];
            f32x4 o4;
            o4[0] = a2 * xr[i][0] + bc * xn4[0];
            o4[1] = a2 * xr[i][1] + bc * xn4[1];
            o4[2] = a2 * xr[i][2] + bc * xn4[2];
            o4[3] = a2 * xr[i][3] + bc * xn4[3];
            *(f32x4*)(out + (size_t)(n0 + sr) * 128 + c4) = o4;
        }
    }
}

extern "C" void kernel_launch(void* const* d_in, const int* in_sizes, int n_in,
                              void* d_out, int out_size, void* d_ws, size_t ws_size,
                              hipStream_t stream) {
    (void)in_sizes; (void)n_in; (void)out_size;
    const float* x    = (const float*)d_in[0];
    const float* Wq_w = (const float*)d_in[2];
    const float* Wq_b = (const float*)d_in[3];
    const float* Wk_w = (const float*)d_in[4];
    const float* Wk_b = (const float*)d_in[5];
    const float* Wv_w = (const float*)d_in[6];
    const float* Wv_b = (const float*)d_in[7];
    const float* Wo_w = (const float*)d_in[8];
    const float* Wo_b = (const float*)d_in[9];
    const float* alpha= (const float*)d_in[10];
    const float* beta = (const float*)d_in[11];
    const float* proj = (const float*)d_in[12];
    float* out = (float*)d_out;
    float* ws  = (float*)d_ws;

    float* kmax     = ws + WS_KMAX;
    float* red2     = ws + WS_RED2;
    float* partials = ws + WS_PART;
    const size_t availf = (ws_size / 4 > (size_t)WS_PART) ? (ws_size / 4 - WS_PART) : 0;
    int nb = (int)(availf / 16896);
    if (nb > 256) nb = 256;
    if (nb < 1) nb = 1;

    prep_kernel<<<1032, 256, 0, stream>>>(Wq_w, Wq_b, Wk_w, Wk_b, Wv_w, Wv_b, Wo_w, proj, ws);
    kmax_mfma_kernel<<<512, 512, 0, stream>>>(x, ws, kmax);
    kvs_mfma_kernel<<<nb, 512, 0, stream>>>(x, ws, partials, nb);
    reduce1_kernel<<<528, 256, 0, stream>>>(partials, red2, nb);
    reduce2_kernel<<<66, 256, 0, stream>>>(red2, ws);
    out_mfma_kernel<<<3125, 512, 0, stream>>>(x, ws, alpha, beta, Wo_b, out);
}

// Round 16
// 279.747 us; speedup vs baseline: 1.2446x; 1.0853x over previous
//
#include <hip/hip_runtime.h>
#include <math.h>

#define NN 100000
#define SCALE 0.8408964152537145f  // inv_sqrt_tau(=2) * 32^-0.25
#define HALF_SCALE2 0.3535533905932738f // 0.5 * SCALE^2
#define RATIO 0.125f               // 64^-0.5
#define KEPS 1e-6f
#define PSTR 17160                 // per-block partial stride (floats)
#define RSTR 17152                 // red2 stride (kvs 16384 + ks 512 + Sv 256)

// ws layout (float offsets)
#define WS_KVSKS 8          // 16384 kvs fp32 + 512 ks fp32
#define WS_KVST 16904       // kvsT bf16 [8][32][64] -> 8192 floats
#define WS_B2Q 156168       // 512
#define WS_B2K 156680       // 512
#define WS_W2QT 157192      // bf16 [512][128] -> 32768 floats
#define WS_W2KT 189960      // bf16 [512][128]
#define WS_WQST 222728      // bf16 [256][128] (SCALE*Wq)^T -> 16384 floats
#define WS_WOT 239112       // bf16 [128][256] Wo^T -> 16384 floats
#define WS_BQS 255496       // 256 fp32 (SCALE*Wq_b)
#define WS_WKVT 255752      // bf16 [512][128] [Wk|Wv]^T -> 32768 floats
#define WS_BKV 288520       // 512 fp32 [bk|bv]
#define WS_RED2 289032      // 8*17152 fp32 stage-2 reduce partials
#define WS_SCAL 426248      // nb*8 fp32 per-block head scales
#define WS_PART 428296      // nb * PSTR

typedef __attribute__((ext_vector_type(8))) short short8;
typedef __attribute__((ext_vector_type(4))) float f32x4;

#define MFMA16(a, b, c) __builtin_amdgcn_mfma_f32_16x16x32_bf16((a), (b), (c), 0, 0, 0)

__device__ __forceinline__ short f2bf(float f) {
    union { float f; unsigned u; } a; a.f = f;
    unsigned r = a.u + 0x7fffu + ((a.u >> 16) & 1u);
    return (short)(r >> 16);
}
__device__ __forceinline__ float bf2f(short s) {
    union { float f; unsigned u; } a; a.u = ((unsigned)(unsigned short)s) << 16;
    return a.f;
}

__device__ __forceinline__ float bsum16(float v) {
    v += __shfl_xor(v, 1); v += __shfl_xor(v, 2);
    v += __shfl_xor(v, 4); v += __shfl_xor(v, 8);
    return v;
}
__device__ __forceinline__ float bmax16(float v) {
    v = fmaxf(v, __shfl_xor(v, 1)); v = fmaxf(v, __shfl_xor(v, 2));
    v = fmaxf(v, __shfl_xor(v, 4)); v = fmaxf(v, __shfl_xor(v, 8));
    return v;
}

// ---------- prep (merged): all weight transforms in one launch ----------
__global__ __launch_bounds__(256) void prep_kernel(
    const float* __restrict__ Wq_w, const float* __restrict__ Wq_b,
    const float* __restrict__ Wk_w, const float* __restrict__ Wk_b,
    const float* __restrict__ Wv_w, const float* __restrict__ Wv_b,
    const float* __restrict__ Wo_w, const float* __restrict__ proj,
    float* __restrict__ ws)
{
    int idx = blockIdx.x * 256 + threadIdx.x;
    const int ftotal = 129 * 512;
    if (idx < 2 * ftotal) {  // fold: W2QT / W2KT + b2q / b2k
        const int mat = (idx >= ftotal) ? 1 : 0;
        idx -= mat * ftotal;
        const int row = idx >> 9;
        const int col = idx & 511;
        const int h = col >> 6, m = col & 63;
        const float* W = mat ? Wk_w : Wq_w;
        const float* b = mat ? Wk_b : Wq_b;
        const float* src = (row < 128) ? (W + row * 256 + h * 32) : (b + h * 32);
        float s = 0.f;
#pragma unroll
        for (int d = 0; d < 32; ++d) s = fmaf(src[d], proj[m * 32 + d], s);
        s *= SCALE;
        if (row < 128) ((short*)(ws + (mat ? WS_W2KT : WS_W2QT)))[col * 128 + row] = f2bf(s);
        else           ws[(mat ? WS_B2K : WS_B2Q) + col] = s;
        return;
    }
    idx -= 2 * ftotal;
    if (idx < 32768) {  // WqsT [256][128]
        int c = idx >> 7, k = idx & 127;
        ((short*)(ws + WS_WQST))[idx] = f2bf(SCALE * Wq_w[k * 256 + c]);
        return;
    }
    idx -= 32768;
    if (idx < 32768) {  // WoT [128][256]
        int o = idx >> 8, c = idx & 255;
        ((short*)(ws + WS_WOT))[idx] = f2bf(Wo_w[c * 128 + o]);
        return;
    }
    idx -= 32768;
    if (idx < 256) { ws[WS_BQS + idx] = SCALE * Wq_b[idx]; return; }
    idx -= 256;
    if (idx < 65536) {  // WkvT [512][128]
        int c = idx >> 7, k = idx & 127;
        ((short*)(ws + WS_WKVT))[idx] =
            f2bf(c < 256 ? Wk_w[k * 256 + c] : Wv_w[k * 256 + (c - 256)]);
        return;
    }
    idx -= 65536;
    if (idx < 512) ws[WS_BKV + idx] = (idx < 256) ? Wk_b[idx] : Wv_b[idx - 256];
}

// ---------- kvs: 512 threads, wave = head, hoisted weights + ONLINE per-hf max ----------
__global__ __launch_bounds__(512, 2) void kvs_mfma_kernel(
    const float* __restrict__ x, const float* __restrict__ ws,
    float* __restrict__ partials, int nb)
{
    __shared__ char smem[57344];
    const short* wkvt = (const short*)(ws + WS_WKVT);
    const short* w2kt = (const short*)(ws + WS_W2KT);
    const float* bkv  = ws + WS_BKV;
    const float* b2k  = ws + WS_B2K;

    const int t = threadIdx.x, w = t >> 6, l = t & 63, lg = l >> 4, li = l & 15;
    char* kptb = smem + 8192 + w * 4096;
    char* vtb  = smem + 40960 + w * 2048;
    float bkv_r[4], b2_r[4];
#pragma unroll
    for (int nc = 0; nc < 4; ++nc) {
        bkv_r[nc] = (nc < 2) ? bkv[w * 32 + nc * 16 + li] : bkv[256 + w * 32 + (nc - 2) * 16 + li];
        b2_r[nc]  = b2k[w * 64 + nc * 16 + li];
    }

    short8 Bkv[16], B2k[16];
#pragma unroll
    for (int hf = 0; hf < 2; ++hf)
#pragma unroll
        for (int kk = 0; kk < 4; ++kk)
#pragma unroll
            for (int nc = 0; nc < 2; ++nc) {
                const int brow = (hf == 0 ? w * 32 : 256 + w * 32) + nc * 16 + li;
                Bkv[hf * 8 + kk * 2 + nc] = *(const short8*)&wkvt[brow * 128 + kk * 32 + lg * 8];
                B2k[hf * 8 + kk * 2 + nc] =
                    *(const short8*)&w2kt[(w * 64 + (hf * 2 + nc) * 16 + li) * 128 + kk * 32 + lg * 8];
            }

    f32x4 ak[4][2];
#pragma unroll
    for (int mr = 0; mr < 4; ++mr)
#pragma unroll
        for (int nc = 0; nc < 2; ++nc) ak[mr][nc] = (f32x4){0.f,0.f,0.f,0.f};
    float ksacc[4];
#pragma unroll
    for (int nc = 0; nc < 4; ++nc) ksacc[nc] = 0.f;
    float svacc0 = 0.f, svacc1 = 0.f;
    float m_run = -1e30f;

    for (int tile = blockIdx.x; tile < 3125; tile += nb) {
        const int n0 = tile * 32;
        __syncthreads();
        {
            const int sr = t >> 4, sp = t & 15;
            const float* gp = x + (size_t)(n0 + sr) * 128 + sp * 8;
            f32x4 v0 = *(const f32x4*)gp, v1 = *(const f32x4*)(gp + 4);
            short8 s;
#pragma unroll
            for (int e = 0; e < 4; ++e) { s[e] = f2bf(v0[e]); s[4 + e] = f2bf(v1[e]); }
            *(short8*)(smem + sr * 256 + ((sp * 16) ^ ((sr & 7) << 4))) = s;
        }
        __syncthreads();
        float dgk[2][4];
        // ---- GEMM1: k (hf=0, diag) then v (hf=1, vT + Sv) ----
#pragma unroll
        for (int hf = 0; hf < 2; ++hf) {
            f32x4 acc[2][2];
#pragma unroll
            for (int mr = 0; mr < 2; ++mr)
#pragma unroll
                for (int nc = 0; nc < 2; ++nc) acc[mr][nc] = (f32x4){0.f,0.f,0.f,0.f};
#pragma unroll
            for (int kk = 0; kk < 4; ++kk)
#pragma unroll
                for (int mr = 0; mr < 2; ++mr) {
                    const int row = mr * 16 + li;
                    const short8 a = *(const short8*)(smem + row * 256 + (((kk * 32 + lg * 8) * 2) ^ ((row & 7) << 4)));
#pragma unroll
                    for (int nc = 0; nc < 2; ++nc) acc[mr][nc] = MFMA16(a, Bkv[hf * 8 + kk * 2 + nc], acc[mr][nc]);
                }
            if (hf == 0) {
#pragma unroll
                for (int mr = 0; mr < 2; ++mr)
#pragma unroll
                    for (int r = 0; r < 4; ++r) {
                        const float v0 = acc[mr][0][r] + bkv_r[0];
                        const float v1 = acc[mr][1][r] + bkv_r[1];
                        dgk[mr][r] = HALF_SCALE2 * bsum16(v0 * v0 + v1 * v1);
                    }
            } else {
#pragma unroll
                for (int mr = 0; mr < 2; ++mr)
#pragma unroll
                    for (int nc = 0; nc < 2; ++nc) {
                        short4 s4;
                        const float vv0 = acc[mr][nc][0] + bkv_r[2 + nc];
                        const float vv1 = acc[mr][nc][1] + bkv_r[2 + nc];
                        const float vv2 = acc[mr][nc][2] + bkv_r[2 + nc];
                        const float vv3 = acc[mr][nc][3] + bkv_r[2 + nc];
                        if (nc == 0) svacc0 += (vv0 + vv1) + (vv2 + vv3);
                        else         svacc1 += (vv0 + vv1) + (vv2 + vv3);
                        s4.x = f2bf(vv0); s4.y = f2bf(vv1); s4.z = f2bf(vv2); s4.w = f2bf(vv3);
                        const int vrow = nc * 16 + li;
                        const int b = 32 * mr + 8 * lg;
                        *(short4*)(vtb + vrow * 64 +
                                   ((((b >> 4) ^ ((vrow >> 1) & 3)) << 4) | (b & 15))) = s4;
                    }
            }
        }
        // ---- GEMM2 per hf: kdash -> per-hf online max -> rescale -> kp -> kpT ----
#pragma unroll
        for (int hf = 0; hf < 2; ++hf) {
            f32x4 acd[2][2];
#pragma unroll
            for (int mr = 0; mr < 2; ++mr)
#pragma unroll
                for (int nc = 0; nc < 2; ++nc) acd[mr][nc] = (f32x4){0.f,0.f,0.f,0.f};
#pragma unroll
            for (int kk = 0; kk < 4; ++kk)
#pragma unroll
                for (int mr = 0; mr < 2; ++mr) {
                    const int row = mr * 16 + li;
                    const short8 a = *(const short8*)(smem + row * 256 + (((kk * 32 + lg * 8) * 2) ^ ((row & 7) << 4)));
#pragma unroll
                    for (int nc = 0; nc < 2; ++nc) acd[mr][nc] = MFMA16(a, B2k[hf * 8 + kk * 2 + nc], acd[mr][nc]);
                }
            // per-hf tile max (wave-wide)
            float tm = -1e30f;
#pragma unroll
            for (int mr = 0; mr < 2; ++mr)
#pragma unroll
                for (int nc = 0; nc < 2; ++nc)
#pragma unroll
                    for (int r = 0; r < 4; ++r)
                        tm = fmaxf(tm, acd[mr][nc][r] + b2_r[hf * 2 + nc]);
            tm = bmax16(tm); tm = fmaxf(tm, __shfl_xor(tm, 16)); tm = fmaxf(tm, __shfl_xor(tm, 32));
            if (tm > m_run) {
                const float s = __expf(m_run - tm);
#pragma unroll
                for (int mr = 0; mr < 4; ++mr)
#pragma unroll
                    for (int nc = 0; nc < 2; ++nc) ak[mr][nc] *= s;
#pragma unroll
                for (int nc = 0; nc < 4; ++nc) ksacc[nc] *= s;
                m_run = tm;
            }
#pragma unroll
            for (int mr = 0; mr < 2; ++mr)
#pragma unroll
                for (int nc = 0; nc < 2; ++nc) {
                    short4 s4;
#pragma unroll
                    for (int r = 0; r < 4; ++r) {
                        const float val = acd[mr][nc][r] + b2_r[hf * 2 + nc];
                        const float e = RATIO * __expf(val - dgk[mr][r] - m_run);
                        const short sb = f2bf(e);
                        ksacc[hf * 2 + nc] += bf2f(sb);
                        if (r == 0) s4.x = sb; else if (r == 1) s4.y = sb;
                        else if (r == 2) s4.z = sb; else s4.w = sb;
                    }
                    const int mrow = (hf * 2 + nc) * 16 + li;
                    const int b = 32 * mr + 8 * lg;
                    *(short4*)(kptb + mrow * 64 +
                               ((((b >> 4) ^ ((mrow >> 1) & 3)) << 4) | (b & 15))) = s4;
                }
        }
        // ---- GEMM3: E += kpT @ v ----
        {
            short8 aa[4], bv[2];
#pragma unroll
            for (int mr = 0; mr < 4; ++mr) {
                const int row = mr * 16 + li;
                aa[mr] = *(const short8*)(kptb + row * 64 + ((lg ^ ((row >> 1) & 3)) << 4));
            }
#pragma unroll
            for (int nc = 0; nc < 2; ++nc) {
                const int vrow = nc * 16 + li;
                bv[nc] = *(const short8*)(vtb + vrow * 64 + ((lg ^ ((vrow >> 1) & 3)) << 4));
            }
#pragma unroll
            for (int mr = 0; mr < 4; ++mr)
#pragma unroll
                for (int nc = 0; nc < 2; ++nc)
                    ak[mr][nc] = MFMA16(aa[mr], bv[nc], ak[mr][nc]);
        }
    }
    float* pb = partials + (size_t)blockIdx.x * PSTR;
#pragma unroll
    for (int mr = 0; mr < 4; ++mr)
#pragma unroll
        for (int nc = 0; nc < 2; ++nc)
#pragma unroll
            for (int r = 0; r < 4; ++r) {
                const int m = mr * 16 + lg * 4 + r;
                const int d = nc * 16 + li;
                pb[(w * 64 + m) * 32 + d] = ak[mr][nc][r];
            }
#pragma unroll
    for (int nc = 0; nc < 4; ++nc) {
        float s = ksacc[nc];
        s += __shfl_xor(s, 16); s += __shfl_xor(s, 32);
        if (lg == 0) pb[16384 + w * 64 + nc * 16 + li] = s;
    }
    {
        float sv = svacc0;
        sv += __shfl_xor(sv, 16); sv += __shfl_xor(sv, 32);
        if (lg == 0) pb[16896 + w * 32 + li] = sv;
        float sv1 = svacc1;
        sv1 += __shfl_xor(sv1, 16); sv1 += __shfl_xor(sv1, 32);
        if (lg == 0) pb[16896 + w * 32 + 16 + li] = sv1;
    }
    if (l == 0) pb[17152 + w] = m_run;
}

// ---------- reduce0: per-head global max + per-block scales ----------
__global__ __launch_bounds__(256) void reduce0_kernel(
    const float* __restrict__ partials, float* __restrict__ scal, int nb)
{
    __shared__ float sm[256];
    __shared__ float kmS[8];
    const int t = threadIdx.x;
    const int h = t & 7, j = t >> 3;   // 32 threads per head
    float m = -1e30f;
    for (int q = j; q < nb; q += 32)
        m = fmaxf(m, partials[(size_t)q * PSTR + 17152 + h]);
    sm[t] = m;
    __syncthreads();
    if (t < 8) {
        float mm = -1e30f;
#pragma unroll
        for (int i = 0; i < 32; ++i) mm = fmaxf(mm, sm[t + 8 * i]);
        kmS[t] = mm;
    }
    __syncthreads();
    for (int i = t; i < nb * 8; i += 256) {
        const int q = i >> 3, hh = i & 7;
        scal[i] = __expf(partials[(size_t)q * PSTR + 17152 + hh] - kmS[hh]);
    }
}

// ---------- reduce1: scaled partial sums ----------
__global__ __launch_bounds__(256) void reduce1_kernel(
    const float* __restrict__ partials, const float* __restrict__ scal,
    float* __restrict__ red2, int nb)
{
    const int b = blockIdx.x;
    const int part = b & 7, grp = b >> 3;
    const int idx = grp * 256 + threadIdx.x;
    if (idx >= RSTR) return;
    const int per = (nb + 7) >> 3;
    const int lo = part * per;
    const int hi = (lo + per < nb) ? (lo + per) : nb;
    int h = 0; bool scaled = true;
    if (idx < 16384) h = idx >> 11;
    else if (idx < 16896) h = (idx - 16384) >> 6;
    else scaled = false;
    float s = 0.f;
    for (int q = lo; q < hi; ++q) {
        const float p = partials[(size_t)q * PSTR + idx];
        s += scaled ? p * scal[q * 8 + h] : p;
    }
    red2[(size_t)part * RSTR + idx] = s;
}

__global__ __launch_bounds__(256) void reduce2_kernel(
    const float* __restrict__ red2, float* __restrict__ ws)
{
    const int idx = blockIdx.x * 256 + threadIdx.x;
    if (idx >= 16896) return;
    float s = 0.f;
#pragma unroll
    for (int p = 0; p < 8; ++p) s += red2[(size_t)p * RSTR + idx];
    float val;
    if (idx < 16384) {
        const int h = idx >> 11, d = idx & 31;
        float sv = 0.f;
#pragma unroll
        for (int p = 0; p < 8; ++p) sv += red2[(size_t)p * RSTR + 16896 + h * 32 + d];
        val = s + RATIO * KEPS * sv;
    } else {
        val = s + RATIO * KEPS * 100000.0f;
    }
    ws[WS_KVSKS + idx] = val;
    if (idx < 16384) {
        const int h = idx >> 11, m = (idx >> 5) & 63, d = idx & 31;
        ((short*)(ws + WS_KVST))[(h * 32 + d) * 64 + m] = f2bf(val);
    }
}

// ---------- out: 512 threads, wave = head, 32 rows/block (R13/R15-frozen) ----------
// smem: [0,8192) xs [32][256B]; [8192,24576) zs [32][512B]; [24576,40960) qp per-wave 2KB
__global__ __launch_bounds__(512, 4) void out_mfma_kernel(
    const float* __restrict__ x, const float* __restrict__ ws,
    const float* __restrict__ alpha, const float* __restrict__ beta,
    const float* __restrict__ Wo_b, float* __restrict__ out)
{
    __shared__ char smem[40960];
    const short* wqst = (const short*)(ws + WS_WQST);
    const short* w2qt = (const short*)(ws + WS_W2QT);
    const short* wot  = (const short*)(ws + WS_WOT);
    const short* kvst = (const short*)(ws + WS_KVST);
    const float* bqs  = ws + WS_BQS;
    const float* b2q  = ws + WS_B2Q;
    const float* ksum = ws + WS_KVSKS + 16384;

    const int t = threadIdx.x, w = t >> 6, l = t & 63, lg = l >> 4, li = l & 15;
    const float a_ = __expf(alpha[0]), b_ = __expf(beta[0]);
    const float a2 = a_ * a_, bc = b_ * (a_ + 1.f);
    char* qpb = smem + 24576 + w * 2048;

    float bq_r[2], b2_r[4], ksv[4];
#pragma unroll
    for (int nc = 0; nc < 2; ++nc) bq_r[nc] = bqs[w * 32 + nc * 16 + li];
#pragma unroll
    for (int nc = 0; nc < 4; ++nc) {
        b2_r[nc] = b2q[w * 64 + nc * 16 + li];
        ksv[nc]  = ksum[w * 64 + nc * 16 + li];
    }
    const float bo = Wo_b[w * 16 + li];

    const int n0 = blockIdx.x * 32;
    f32x4 xr[2];
    {
        const int c4 = (t & 31) * 4;
#pragma unroll
        for (int i = 0; i < 2; ++i) {
            const int sr = (t >> 5) + i * 16;
            xr[i] = *(const f32x4*)(x + (size_t)(n0 + sr) * 128 + c4);
            short4 s4;
            s4.x = f2bf(xr[i][0]); s4.y = f2bf(xr[i][1]);
            s4.z = f2bf(xr[i][2]); s4.w = f2bf(xr[i][3]);
            *(short4*)(smem + sr * 256 + ((c4 * 2) ^ ((sr & 7) << 4))) = s4;
        }
    }
    __syncthreads();
    float dg[2][4];
    {
        short8 Bq[8];
#pragma unroll
        for (int kk = 0; kk < 4; ++kk)
#pragma unroll
            for (int nc = 0; nc < 2; ++nc)
                Bq[kk * 2 + nc] = *(const short8*)&wqst[(w * 32 + nc * 16 + li) * 128 + kk * 32 + lg * 8];
#pragma unroll
        for (int mr = 0; mr < 2; ++mr) {
            f32x4 aq[2];
#pragma unroll
            for (int nc = 0; nc < 2; ++nc) aq[nc] = (f32x4){0.f,0.f,0.f,0.f};
#pragma unroll
            for (int kk = 0; kk < 4; ++kk) {
                const int row = mr * 16 + li;
                const short8 a = *(const short8*)(smem + row * 256 + (((kk * 32 + lg * 8) * 2) ^ ((row & 7) << 4)));
#pragma unroll
                for (int nc = 0; nc < 2; ++nc) aq[nc] = MFMA16(a, Bq[kk * 2 + nc], aq[nc]);
            }
#pragma unroll
            for (int r = 0; r < 4; ++r) {
                const float v0 = aq[0][r] + bq_r[0], v1 = aq[1][r] + bq_r[1];
                dg[mr][r] = 0.5f * bsum16(v0 * v0 + v1 * v1);
            }
        }
    }
    short8 Kf[4];
#pragma unroll
    for (int kk = 0; kk < 2; ++kk)
#pragma unroll
        for (int nc = 0; nc < 2; ++nc)
            Kf[kk * 2 + nc] = *(const short8*)&kvst[(w * 32 + nc * 16 + li) * 64 + kk * 32 + lg * 8];
#pragma unroll
    for (int mr = 0; mr < 2; ++mr) {
        f32x4 ad[4];
#pragma unroll
        for (int hf = 0; hf < 2; ++hf) {
            short8 Bf[8];
#pragma unroll
            for (int kk = 0; kk < 4; ++kk)
#pragma unroll
                for (int nc = 0; nc < 2; ++nc)
                    Bf[kk * 2 + nc] = *(const short8*)&w2qt[(w * 64 + (hf * 2 + nc) * 16 + li) * 128 + kk * 32 + lg * 8];
            f32x4 a0 = (f32x4){0.f,0.f,0.f,0.f}, a1 = (f32x4){0.f,0.f,0.f,0.f};
#pragma unroll
            for (int kk = 0; kk < 4; ++kk) {
                const int row = mr * 16 + li;
                const short8 a = *(const short8*)(smem + row * 256 + (((kk * 32 + lg * 8) * 2) ^ ((row & 7) << 4)));
                a0 = MFMA16(a, Bf[kk * 2 + 0], a0);
                a1 = MFMA16(a, Bf[kk * 2 + 1], a1);
            }
            ad[hf * 2 + 0] = a0; ad[hf * 2 + 1] = a1;
        }
        float zd[4];
#pragma unroll
        for (int r = 0; r < 4; ++r) {
            float vv[4];
#pragma unroll
            for (int nc = 0; nc < 4; ++nc) vv[nc] = ad[nc][r] + b2_r[nc];
            float mx = fmaxf(fmaxf(vv[0], vv[1]), fmaxf(vv[2], vv[3]));
            mx = bmax16(mx);
            const int rr = lg * 4 + r;
            const int sw = (rr & 7) << 4;
            float z = 0.f;
#pragma unroll
            for (int nc = 0; nc < 4; ++nc) {
                const float e = RATIO * (__expf(vv[nc] - dg[mr][r] - mx) + KEPS);
                z = fmaf(e, ksv[nc], z);
                *(short*)(qpb + rr * 128 + ((nc * 32 + 2 * li) ^ sw)) = f2bf(e);
            }
            zd[r] = bsum16(z);
        }
        f32x4 az[2];
#pragma unroll
        for (int nc = 0; nc < 2; ++nc) az[nc] = (f32x4){0.f,0.f,0.f,0.f};
#pragma unroll
        for (int kk = 0; kk < 2; ++kk) {
            const short8 aa = *(const short8*)(qpb + li * 128 +
                              ((kk * 64 + lg * 16) ^ ((li & 7) << 4)));
#pragma unroll
            for (int nc = 0; nc < 2; ++nc) az[nc] = MFMA16(aa, Kf[kk * 2 + nc], az[nc]);
        }
#pragma unroll
        for (int nc = 0; nc < 2; ++nc)
#pragma unroll
            for (int r = 0; r < 4; ++r) {
                const int row = mr * 16 + lg * 4 + r;
                const float zv = az[nc][r] / zd[r];
                *(short*)(smem + 8192 + row * 512 +
                    ((2 * (w * 32 + nc * 16 + li)) ^ ((row & 7) << 4))) = f2bf(zv);
            }
    }
    short8 Bo[8];
#pragma unroll
    for (int kk = 0; kk < 8; ++kk)
        Bo[kk] = *(const short8*)&wot[(w * 16 + li) * 256 + kk * 32 + lg * 8];
    __syncthreads();
    f32x4 ao[2];
#pragma unroll
    for (int mr = 0; mr < 2; ++mr) ao[mr] = (f32x4){0.f,0.f,0.f,0.f};
#pragma unroll
    for (int mr = 0; mr < 2; ++mr)
#pragma unroll
        for (int kk = 0; kk < 8; ++kk) {
            const int row = mr * 16 + li;
            const short8 aa = *(const short8*)(smem + 8192 + row * 512 +
                              ((kk * 64 + lg * 16) ^ ((row & 7) << 4)));
            ao[mr] = MFMA16(aa, Bo[kk], ao[mr]);
        }
    __syncthreads();
    float* xnb = (float*)smem;
#pragma unroll
    for (int mr = 0; mr < 2; ++mr)
#pragma unroll
        for (int r = 0; r < 4; ++r) {
            const int row = mr * 16 + lg * 4 + r;
            xnb[row * 132 + w * 16 + li] = ao[mr][r] + bo;
        }
    __syncthreads();
    {
        const int c4 = (t & 31) * 4;
#pragma unroll
        for (int i = 0; i < 2; ++i) {
            const int sr = (t >> 5) + i * 16;
            const f32x4 xn4 = *(const f32x4*)&xnb[sr * 132 + c4];
            f32x4 o4;
            o4[0] = a2 * xr[i][0] + bc * xn4[0];
            o4[1] = a2 * xr[i][1] + bc * xn4[1];
            o4[2] = a2 * xr[i][2] + bc * xn4[2];
            o4[3] = a2 * xr[i][3] + bc * xn4[3];
            *(f32x4*)(out + (size_t)(n0 + sr) * 128 + c4) = o4;
        }
    }
}

extern "C" void kernel_launch(void* const* d_in, const int* in_sizes, int n_in,
                              void* d_out, int out_size, void* d_ws, size_t ws_size,
                              hipStream_t stream) {
    (void)in_sizes; (void)n_in; (void)out_size;
    const float* x    = (const float*)d_in[0];
    const float* Wq_w = (const float*)d_in[2];
    const float* Wq_b = (const float*)d_in[3];
    const float* Wk_w = (const float*)d_in[4];
    const float* Wk_b = (const float*)d_in[5];
    const float* Wv_w = (const float*)d_in[6];
    const float* Wv_b = (const float*)d_in[7];
    const float* Wo_w = (const float*)d_in[8];
    const float* Wo_b = (const float*)d_in[9];
    const float* alpha= (const float*)d_in[10];
    const float* beta = (const float*)d_in[11];
    const float* proj = (const float*)d_in[12];
    float* out = (float*)d_out;
    float* ws  = (float*)d_ws;

    float* red2     = ws + WS_RED2;
    float* scal     = ws + WS_SCAL;
    float* partials = ws + WS_PART;
    const size_t availf = (ws_size / 4 > (size_t)WS_PART) ? (ws_size / 4 - WS_PART) : 0;
    int nb = (int)(availf / PSTR);
    if (nb > 256) nb = 256;
    if (nb < 1) nb = 1;

    prep_kernel<<<1032, 256, 0, stream>>>(Wq_w, Wq_b, Wk_w, Wk_b, Wv_w, Wv_b, Wo_w, proj, ws);
    kvs_mfma_kernel<<<nb, 512, 0, stream>>>(x, ws, partials, nb);
    reduce0_kernel<<<1, 256, 0, stream>>>(partials, scal, nb);
    reduce1_kernel<<<536, 256, 0, stream>>>(partials, scal, red2, nb);
    reduce2_kernel<<<66, 256, 0, stream>>>(red2, ws);
    out_mfma_kernel<<<3125, 512, 0, stream>>>(x, ws, alpha, beta, Wo_b, out);
}